// Round 2
// baseline (116.114 us; speedup 1.0000x reference)
//
#include <hip/hip_runtime.h>
#include <hip/hip_bf16.h>

// Z[b,w,t] = sum_c Q[b,w,c] * (K[b,w+t,c] + bias[c,t])
// B=16, T=1024, C=128, K has 2T-1=2047 rows.
//
// Round 4: persistent-tile main kernel (round-3 structure) + fix: the K band
// per block spans 17 chunks (0..16: rows w0..w0+1086), so the ring prefetch
// must run through s=14 staging chunk 16 (was s<14 -> chunk 15 max -> stale
// data read at the last t0 step). 256 blocks (1/CU), 8 waves, BW=64 Q rows,
// 16 t0-steps of BT=64. K slides through a 3-slot ring; bias double-buffered;
// Q held in registers. Schedule: prefetch -> compute -> lgkm+bar -> vmcnt(0)
// -> epilogue -> bar.

#define B_    16
#define T_    1024
#define C_    128
#define KT_   2047

// fallback tile params (round-1 kernel)
#define BW    32
#define BT    64
#define KROWS 96
#define SS_LD 98
#define LDB   136

// main kernel Ss leading dim (f32): 130 -> 2-way (free) write banks, ~3-way reads
#define LDSS  130

typedef unsigned short ushort_t;
typedef short bf16x8 __attribute__((ext_vector_type(8)));
typedef float f32x4  __attribute__((ext_vector_type(4)));

__device__ __forceinline__ unsigned short f2bf(float f) {
  unsigned int u = __float_as_uint(f);
  u += 0x7FFFu + ((u >> 16) & 1u);
  return (unsigned short)(u >> 16);
}

__device__ __forceinline__ bf16x8 pack8(float4 lo, float4 hi) {
  bf16x8 r;
  r[0] = (short)f2bf(lo.x); r[1] = (short)f2bf(lo.y);
  r[2] = (short)f2bf(lo.z); r[3] = (short)f2bf(lo.w);
  r[4] = (short)f2bf(hi.x); r[5] = (short)f2bf(hi.y);
  r[6] = (short)f2bf(hi.z); r[7] = (short)f2bf(hi.w);
  return r;
}

typedef const __attribute__((address_space(1))) unsigned int* gas_ptr;
typedef __attribute__((address_space(3))) unsigned int* las_ptr;
__device__ __forceinline__ void async_copy16(const void* g, void* l) {
  __builtin_amdgcn_global_load_lds((gas_ptr)g, (las_ptr)l, 16, 0, 0);
}

// swizzled fragment pointer: chunk kc (8 bf16) of LDS row `row` (128 bf16/row)
__device__ __forceinline__ const bf16x8* frag(const ushort_t* t, int row, int kc) {
  return (const bf16x8*)(t + (((row << 4) + (kc ^ (row & 7))) << 3));
}

// ---------------- pre-pass: K f32->bf16, bias f32->bf16 transposed ----------------
#define KN4 1048064   // 16*2047*128/4
#define BN4 32768     // 128*1024/4

__global__ __launch_bounds__(256) void prepass(
    const float* __restrict__ K, const float* __restrict__ bias,
    ushort_t* __restrict__ Kb, ushort_t* __restrict__ bT) {
  int idx = blockIdx.x * 256 + threadIdx.x;
  if (idx < KN4) {
    float4 v = ((const float4*)K)[idx];
    ((ushort4*)Kb)[idx] = make_ushort4(f2bf(v.x), f2bf(v.y), f2bf(v.z), f2bf(v.w));
  } else {
    int i = idx - KN4;        // < BN4 (grid sized exactly)
    int c = i >> 8;           // 0..127
    int g = i & 255;          // group of 4 along t
    float4 v = ((const float4*)(bias + c * T_))[g];
    int t = g << 2;
    bT[(t + 0) * C_ + c] = f2bf(v.x);
    bT[(t + 1) * C_ + c] = f2bf(v.y);
    bT[(t + 2) * C_ + c] = f2bf(v.z);
    bT[(t + 3) * C_ + c] = f2bf(v.w);
  }
}

// ---------------- main kernel (persistent over t0) ----------------
// LDS rows of 128 bf16 (16 chunks of 16B), XOR-swizzled:
//   rows   0..191 : K ring, 3 slots x 64 rows (slot p at row 64p)
//   rows 192..319 : bias^T, 2 bufs x 64 rows (buf q at row 192+64q)
// Ss: separate f32 [64][LDSS] band scratch.
__global__ __launch_bounds__(512) void swmm_main(
    const float* __restrict__ Q, const ushort_t* __restrict__ Kb,
    const ushort_t* __restrict__ bT, float* __restrict__ out) {
  __shared__ __align__(16) ushort_t tile[5120 * 8];   // 80 KB
  __shared__ __align__(16) float Ss[64 * LDSS];       // 33.3 KB

  const int b    = blockIdx.x;
  const int w0   = blockIdx.y * 64;
  const int tid  = threadIdx.x;
  const int wv   = tid >> 6;
  const int lane = tid & 63;
  const int frow = lane & 15;
  const int quad = lane >> 4;
  const int mpair = wv & 1;        // m-pair {0,32} or {16,48}
  const int wslot = wv >> 1;       // 0..3
  const int m0a = mpair * 16;
  const int m0b = m0a + 32;
  const int j0  = ((wslot + 1) & 3) * 16;   // this wave's output/bias column block

  // staging per-thread constants (pre-swizzled global source, linear LDS dest)
  const int r0 = tid >> 4;                  // 0..31
  const int cc = (tid & 15) ^ (r0 & 7);     // source chunk, XOR pre-applied
  const ushort_t* kbb = Kb + (size_t)b * KT_ * C_ + (cc << 3);
  const ushort_t* btb = bT + (cc << 3);

  auto stageK = [&](int chunk, int p) {
    int g0 = w0 + chunk * 64 + r0;          // <= 2015, always in range
    int g1 = g0 + 32;
    if (g1 > KT_ - 1) g1 = KT_ - 1;         // chunk-16 tail row: unused, clamp addr
    async_copy16(kbb + (size_t)g0 * C_, &tile[(size_t)(p * 1024 + wv * 64) * 8]);
    async_copy16(kbb + (size_t)g1 * C_, &tile[(size_t)(p * 1024 + 512 + wv * 64) * 8]);
  };
  auto stageB = [&](int step, int q) {
    const ushort_t* g = btb + (size_t)(step * 64 + r0) * C_;
    async_copy16(g,           &tile[(size_t)(3072 + q * 1024 + wv * 64) * 8]);
    async_copy16(g + 32 * C_, &tile[(size_t)(3072 + q * 1024 + 512 + wv * 64) * 8]);
  };

  // ---- prologue: stage chunk0, chunk1, bias0; load Q frags to registers ----
  stageK(0, 0); stageK(1, 1); stageB(0, 0);

  bf16x8 aA[4], aB[4];
  {
    const float* qa = Q + ((size_t)(b * T_ + w0 + m0a + frow) << 7);
    const float* qb = qa + (32 << 7);
#pragma unroll
    for (int kk = 0; kk < 4; ++kk) {
      int co = (kk * 4 + quad) << 3;
      float4 lo = *(const float4*)(qa + co);
      float4 hi = *(const float4*)(qa + co + 4);
      aA[kk] = pack8(lo, hi);
      lo = *(const float4*)(qb + co);
      hi = *(const float4*)(qb + co + 4);
      aB[kk] = pack8(lo, hi);
    }
  }

  asm volatile("s_waitcnt vmcnt(0)" ::: "memory");
  __builtin_amdgcn_s_barrier();

  int p0 = 0, p1 = 1, p2 = 2;   // ring slots holding chunks s, s+1, s+2
  f32x4 baccA = {0.f, 0.f, 0.f, 0.f}, baccB = {0.f, 0.f, 0.f, 0.f};

  for (int s = 0; s < 16; ++s) {
    const int q0 = s & 1;

    // ---- prefetch next K chunk + next bias tile (in flight across compute) ----
    // chunks 2..16 staged here (17 chunks total: band spans rows w0..w0+1086)
    if (s < 15) stageK(s + 2, p2);
    if (s < 15) stageB(s + 1, q0 ^ 1);

    // ---- compute: tasks t = wslot, wslot+4, wslot+8 ----
    // t<=6: S band task, n0 = m0a+16t, tileA if t<=4, tileB if t>=2
    // t in 7..10: bias GEMM task for column j0=(t-7)*16 (== this wave's j0)
    __builtin_amdgcn_s_setprio(1);
#pragma unroll
    for (int ti = 0; ti < 3; ++ti) {
      const int t = wslot + ti * 4;
      if (t <= 6) {
        const int n0 = m0a + t * 16;                      // 0..112, n0&63 <= 48
        const int pc = (n0 >> 6) ? p1 : p0;
        const int lrow = pc * 64 + ((n0 + frow) & 63);
        f32x4 accA = {0.f, 0.f, 0.f, 0.f};
        f32x4 accB = {0.f, 0.f, 0.f, 0.f};
#pragma unroll
        for (int kk = 0; kk < 4; ++kk) {
          bf16x8 bb = *frag(tile, lrow, kk * 4 + quad);   // shared by both m-tiles
          if (t <= 4) accA = __builtin_amdgcn_mfma_f32_16x16x32_bf16(aA[kk], bb, accA, 0, 0, 0);
          if (t >= 2) accB = __builtin_amdgcn_mfma_f32_16x16x32_bf16(aB[kk], bb, accB, 0, 0, 0);
        }
        if (t <= 4) {
#pragma unroll
          for (int r = 0; r < 4; ++r)
            Ss[(m0a + quad * 4 + r) * LDSS + n0 + frow] = accA[r];
        }
        if (t >= 2) {
#pragma unroll
          for (int r = 0; r < 4; ++r)
            Ss[(m0b + quad * 4 + r) * LDSS + n0 + frow] = accB[r];
        }
      } else if (t <= 10) {
        const int brow = 192 + q0 * 64 + j0 + frow;
        f32x4 xA = {0.f, 0.f, 0.f, 0.f};
        f32x4 xB = {0.f, 0.f, 0.f, 0.f};
#pragma unroll
        for (int kk = 0; kk < 4; ++kk) {
          bf16x8 bb = *frag(tile, brow, kk * 4 + quad);
          xA = __builtin_amdgcn_mfma_f32_16x16x32_bf16(aA[kk], bb, xA, 0, 0, 0);
          xB = __builtin_amdgcn_mfma_f32_16x16x32_bf16(aB[kk], bb, xB, 0, 0, 0);
        }
        baccA = xA; baccB = xB;
      }
      // t == 11 (wslot 3, ti 2): no task
    }
    __builtin_amdgcn_s_setprio(0);

    asm volatile("s_waitcnt lgkmcnt(0)" ::: "memory");   // Ss writes + frag reads done
    __builtin_amdgcn_s_barrier();
    asm volatile("s_waitcnt vmcnt(0)" ::: "memory");     // prefetch landed (full compute to hide)

    // ---- epilogue: Z[i][j] = bias_acc + S[i][i+j] ----
    {
      float* op = out + ((size_t)(b * T_ + w0) * T_) + s * 64 + j0 + frow;
#pragma unroll
      for (int mi = 0; mi < 2; ++mi) {
        const int m = mi ? m0b : m0a;
        const f32x4 acc = mi ? baccB : baccA;
#pragma unroll
        for (int r = 0; r < 4; ++r) {
          const int i = m + quad * 4 + r;
          op[(size_t)i * T_] = acc[r] + Ss[i * LDSS + i + j0 + frow];
        }
      }
    }
    asm volatile("s_waitcnt lgkmcnt(0)" ::: "memory");   // epilogue Ss reads done
    __builtin_amdgcn_s_barrier();                         // safe to overwrite ring/bias/Ss

    const int tp = p0; p0 = p1; p1 = p2; p2 = tp;
  }
}

// ---------------- fallback (round-1 kernel) if ws too small ----------------
__global__ __launch_bounds__(256) void swmm_fallback(
    const float* __restrict__ Q, const float* __restrict__ K,
    const float* __restrict__ bias, float* __restrict__ out) {
  __shared__ __align__(16) unsigned short Qs[BW * LDB];
  __shared__ __align__(16) unsigned short Ks[KROWS * LDB];
  __shared__ __align__(16) unsigned short Bs[BT * LDB];
  __shared__ __align__(16) float Ssf[BW * SS_LD];

  const int b   = blockIdx.z;
  const int w0  = blockIdx.y * BW;
  const int t0  = blockIdx.x * BT;
  const int kbase = w0 + t0;
  const int tid = threadIdx.x;

  {
    const float4* src = (const float4*)(Q + (size_t)(b * T_ + w0) * C_);
    for (int v = tid; v < BW * (C_ / 4); v += 256) {
      int r = v >> 5, cc = v & 31;
      float4 q = src[r * 32 + cc];
      unsigned short* d = &Qs[r * LDB + (cc << 2)];
      d[0] = f2bf(q.x); d[1] = f2bf(q.y); d[2] = f2bf(q.z); d[3] = f2bf(q.w);
    }
  }
  {
    for (int v = tid; v < KROWS * (C_ / 4); v += 256) {
      int r = v >> 5, cc = v & 31;
      int g = kbase + r;
      float4 kv = make_float4(0.f, 0.f, 0.f, 0.f);
      if (g < KT_) kv = ((const float4*)(K + ((size_t)b * KT_ + g) * C_))[cc];
      unsigned short* d = &Ks[r * LDB + (cc << 2)];
      d[0] = f2bf(kv.x); d[1] = f2bf(kv.y); d[2] = f2bf(kv.z); d[3] = f2bf(kv.w);
    }
  }
  {
    for (int v = tid; v < C_ * (BT / 4); v += 256) {
      int c = v >> 4, jj = v & 15;
      float4 bv = ((const float4*)(bias + (size_t)c * T_ + t0))[jj];
      int j4 = jj << 2;
      Bs[(j4 + 0) * LDB + c] = f2bf(bv.x);
      Bs[(j4 + 1) * LDB + c] = f2bf(bv.y);
      Bs[(j4 + 2) * LDB + c] = f2bf(bv.z);
      Bs[(j4 + 3) * LDB + c] = f2bf(bv.w);
    }
  }
  __syncthreads();

  const int wv    = tid >> 6;
  const int lane  = tid & 63;
  const int frow  = lane & 15;
  const int koff  = (lane >> 4) * 8;
  const int drow4 = (lane >> 4) * 4;
  const int NS = KROWS / 16;

  for (int s = wv; s < 2 * NS; s += 4) {
    int mb = s / NS, nn = s % NS;
    int m0 = mb * 16, n0 = nn * 16;
    const unsigned short* arow = &Qs[(m0 + frow) * LDB + koff];
    const unsigned short* brow = &Ks[(n0 + frow) * LDB + koff];
    f32x4 acc = {0.f, 0.f, 0.f, 0.f};
#pragma unroll
    for (int k0 = 0; k0 < C_; k0 += 32) {
      bf16x8 a  = *(const bf16x8*)(arow + k0);
      bf16x8 bb = *(const bf16x8*)(brow + k0);
      acc = __builtin_amdgcn_mfma_f32_16x16x32_bf16(a, bb, acc, 0, 0, 0);
    }
#pragma unroll
    for (int r = 0; r < 4; ++r)
      Ssf[(m0 + drow4 + r) * SS_LD + n0 + frow] = acc[r];
  }

  f32x4 bacc[2];
#pragma unroll
  for (int q = 0; q < 2; ++q) {
    int idx = wv + q * 4;
    int m0 = (idx >> 2) * 16, jj0 = (idx & 3) * 16;
    const unsigned short* arow = &Qs[(m0 + frow) * LDB + koff];
    const unsigned short* brow = &Bs[(jj0 + frow) * LDB + koff];
    f32x4 acc = {0.f, 0.f, 0.f, 0.f};
#pragma unroll
    for (int k0 = 0; k0 < C_; k0 += 32) {
      bf16x8 a  = *(const bf16x8*)(arow + k0);
      bf16x8 bb = *(const bf16x8*)(brow + k0);
      acc = __builtin_amdgcn_mfma_f32_16x16x32_bf16(a, bb, acc, 0, 0, 0);
    }
    bacc[q] = acc;
  }
  __syncthreads();

#pragma unroll
  for (int q = 0; q < 2; ++q) {
    int idx = wv + q * 4;
    int m0 = (idx >> 2) * 16, jj0 = (idx & 3) * 16;
#pragma unroll
    for (int r = 0; r < 4; ++r) {
      int i = m0 + drow4 + r;
      int j = jj0 + frow;
      out[(size_t)(b * T_ + w0 + i) * T_ + t0 + j] = bacc[q][r] + Ssf[i * SS_LD + i + j];
    }
  }
}

extern "C" void kernel_launch(void* const* d_in, const int* in_sizes, int n_in,
                              void* d_out, int out_size, void* d_ws, size_t ws_size,
                              hipStream_t stream) {
  const float* Q    = (const float*)d_in[0];
  const float* K    = (const float*)d_in[1];
  const float* bias = (const float*)d_in[2];
  float* out = (float*)d_out;

  const size_t KB = (size_t)B_ * KT_ * C_ * 2;       // 8.38 MB
  const size_t TB = (size_t)T_ * C_ * 2;             // 0.25 MB

  if (ws_size >= KB + TB) {
    ushort_t* Kb = (ushort_t*)d_ws;
    ushort_t* bT = (ushort_t*)((char*)d_ws + KB);
    prepass<<<(KN4 + BN4) / 256, 256, 0, stream>>>(K, bias, Kb, bT);
    // grid x = b so XCD round-robin (id%8) groups blocks by b -> K reuse in per-XCD L2
    swmm_main<<<dim3(B_, T_ / 64), dim3(512), 0, stream>>>(Q, Kb, bT, out);
  } else {
    swmm_fallback<<<dim3(T_ / BT, T_ / BW, B_), dim3(256), 0, stream>>>(Q, K, bias, out);
  }
}